// Round 2
// baseline (422.891 us; speedup 1.0000x reference)
//
#include <hip/hip_runtime.h>
#include <math.h>

#define HH 1024
#define SS 1024
#define EE 3

typedef __bf16 bf16x8 __attribute__((ext_vector_type(8)));
typedef float floatx4 __attribute__((ext_vector_type(4)));

__device__ __forceinline__ unsigned short f2bf(float f) {
  union { float f; unsigned u; } v; v.f = f;
  unsigned r = 0x7FFFu + ((v.u >> 16) & 1u);
  return (unsigned short)((v.u + r) >> 16);
}
__device__ __forceinline__ unsigned pack2(float lo, float hi) {
#if __has_builtin(__builtin_amdgcn_cvt_pk_bf16_f32)
  auto p = __builtin_amdgcn_cvt_pk_bf16_f32(lo, hi);
  return __builtin_bit_cast(unsigned, p);
#else
  return ((unsigned)f2bf(hi) << 16) | (unsigned)f2bf(lo);
#endif
}

#define GLDS(gp, lp)                                                    \
  __builtin_amdgcn_global_load_lds(                                     \
      (const __attribute__((address_space(1))) void*)(const void*)(gp), \
      (__attribute__((address_space(3))) void*)(void*)(lp), 16, 0, 0)

// ---------- kernel 1: routing (argmax + gate) fused with x -> bf16 ----------
__global__ __launch_bounds__(256) void k_route(
    const float* __restrict__ x,          // [B,3,S,H] fp32
    const float* __restrict__ wg,         // [3,H,3]   fp32
    unsigned short* __restrict__ xb,      // [3,T,H] bf16 out
    int* __restrict__ idx_out,            // [3*T]
    float* __restrict__ gv_out,           // [3*T]
    int T) {
  int gw = (blockIdx.x * 256 + threadIdx.x) >> 6;  // global wave id [0,6144)
  int lane = threadIdx.x & 63;
  int r = gw >> 11;          // branch [0,3)
  int t0 = gw & 2047;        // starting token
  const float* w = wg + (size_t)r * HH * EE;

  // hoist this lane's gate slice: chunks c=0,1; h0 = c*512 + lane*8
  float wreg[2][24];
#pragma unroll
  for (int c = 0; c < 2; ++c) {
    int h0 = c * 512 + lane * 8;
    const float4* wp = reinterpret_cast<const float4*>(w + (size_t)h0 * 3);
#pragma unroll
    for (int j = 0; j < 6; ++j)
      *reinterpret_cast<float4*>(&wreg[c][4 * j]) = wp[j];
  }

  for (int t = t0; t < T; t += 2048) {
    const float* xrow =
        x + (size_t)(((t >> 10) * 3 + r) * SS + (t & 1023)) * HH;
    unsigned short* xbrow = xb + (size_t)(r * T + t) * HH;
    double a0 = 0, a1 = 0, a2 = 0;
#pragma unroll
    for (int c = 0; c < 2; ++c) {
      int h0 = c * 512 + lane * 8;
      float4 xa = *reinterpret_cast<const float4*>(xrow + h0);
      float4 xb4 = *reinterpret_cast<const float4*>(xrow + h0 + 4);
      float xs[8] = {xa.x, xa.y, xa.z, xa.w, xb4.x, xb4.y, xb4.z, xb4.w};
      // fused bf16 write-out (RNE, same as GEMM previously used)
      uint4 pk;
      pk.x = pack2(xs[0], xs[1]); pk.y = pack2(xs[2], xs[3]);
      pk.z = pack2(xs[4], xs[5]); pk.w = pack2(xs[6], xs[7]);
      *reinterpret_cast<uint4*>(xbrow + h0) = pk;
#pragma unroll
      for (int j = 0; j < 8; ++j) {
        double xv = (double)xs[j];
        a0 += xv * (double)wreg[c][3 * j + 0];
        a1 += xv * (double)wreg[c][3 * j + 1];
        a2 += xv * (double)wreg[c][3 * j + 2];
      }
    }
#pragma unroll
    for (int d = 32; d >= 1; d >>= 1) {
      a0 += __shfl_xor(a0, d, 64);
      a1 += __shfl_xor(a1, d, 64);
      a2 += __shfl_xor(a2, d, 64);
    }
    if (lane == 0) {
      int best = 0; double bl = a0;
      if (a1 > bl) { best = 1; bl = a1; }  // strict >: first-max wins
      if (a2 > bl) { best = 2; bl = a2; }
      float g = 1.0f / (expf((float)(a0 - bl)) + expf((float)(a1 - bl)) +
                        expf((float)(a2 - bl)));
      idx_out[r * T + t] = best;
      gv_out[r * T + t] = g;
    }
  }
}

// ------- kernel 2: arrival-order scan (3 blocks) + We fp32->bf16 (rest) -------
__global__ __launch_bounds__(1024) void k_scanconv(
    const int* __restrict__ idx, const float* __restrict__ gv,
    const float* __restrict__ We, unsigned short* __restrict__ wb,
    int* __restrict__ perm,    // [3*3*T] token ids per (branch,expert)
    float* __restrict__ scale, // [3*T]  gate*keep (0 if dropped)
    int* __restrict__ counts,  // [9]
    int T, int C, int n8) {
  if (blockIdx.x >= 3) {
    // ---- convw part: one 8-elem segment per thread ----
    int i = (blockIdx.x - 3) * 1024 + threadIdx.x;
    if (i < n8) {
      const float4* p = reinterpret_cast<const float4*>(We + (size_t)i * 8);
      float4 a = p[0], b = p[1];
      uint4 pk;
      pk.x = pack2(a.x, a.y); pk.y = pack2(a.z, a.w);
      pk.z = pack2(b.x, b.y); pk.w = pack2(b.z, b.w);
      *reinterpret_cast<uint4*>(wb + (size_t)i * 8) = pk;
    }
    return;
  }
  // ---- scan part (blocks 0..2), unchanged logic ----
  int r = blockIdx.x;
  int tid = threadIdx.x;
  int per = T >> 10;  // tokens per thread (T=8192 -> 8)
  int t0 = tid * per;
  const int* idxr = idx + (size_t)r * T;

  int c0 = 0, c1 = 0, c2 = 0;
  for (int k = 0; k < per; ++k) {
    int e = idxr[t0 + k];
    c0 += (e == 0); c1 += (e == 1); c2 += (e == 2);
  }
  int lane = tid & 63, wv = tid >> 6;
  int s0 = c0, s1 = c1, s2 = c2;  // wave inclusive scan
  for (int d = 1; d < 64; d <<= 1) {
    int u0 = __shfl_up(s0, d, 64);
    int u1 = __shfl_up(s1, d, 64);
    int u2 = __shfl_up(s2, d, 64);
    if (lane >= d) { s0 += u0; s1 += u1; s2 += u2; }
  }
  __shared__ int wsum[16][3];
  __shared__ int wbase[16][3];
  if (lane == 63) { wsum[wv][0] = s0; wsum[wv][1] = s1; wsum[wv][2] = s2; }
  __syncthreads();
  if (tid == 0) {
    int b0 = 0, b1 = 0, b2 = 0;
    int nw = blockDim.x >> 6;
    for (int i = 0; i < nw; ++i) {
      wbase[i][0] = b0; wbase[i][1] = b1; wbase[i][2] = b2;
      b0 += wsum[i][0]; b1 += wsum[i][1]; b2 += wsum[i][2];
    }
    counts[r * 3 + 0] = b0; counts[r * 3 + 1] = b1; counts[r * 3 + 2] = b2;
  }
  __syncthreads();
  int off[3];
  off[0] = wbase[wv][0] + s0 - c0;
  off[1] = wbase[wv][1] + s1 - c1;
  off[2] = wbase[wv][2] + s2 - c2;
  for (int k = 0; k < per; ++k) {
    int e = idxr[t0 + k];
    int p = off[e]++;
    perm[(size_t)(r * 3 + e) * T + p] = t0 + k;
    scale[(size_t)r * T + t0 + k] = (p < C) ? gv[(size_t)r * T + t0 + k] : 0.0f;
  }
}

// ---------------- kernel 3: grouped GEMM, 256x256 tile, 8 waves ----------------
// bf16, BM=BN=256, BK=32, 512 threads (8 waves, 2M x 4N). Triple-buffered LDS
// (3 x 32KB), counted s_waitcnt vmcnt(4) fused with raw s_barrier (ONE barrier
// per K-step, never draining in steady state), rotation-swizzled LDS (optimal
// 8-dword/bank ds_read_b128), setprio around the 32-MFMA cluster.
//
// Schedule identical to the round-1-verified 128^2 loop (same race-freedom
// proof): per wave 4 GLDS per K-tile; vmcnt(4) at iter kt guarantees batch kt
// landed while kt+1's 4 stay in flight; STAGE(kt+2) overwrites slot (kt-1)%3
// whose ds_reads all retired before this barrier.
__global__ __launch_bounds__(512, 2) void k_gemm(
    const unsigned short* __restrict__ xb,  // [3,T,H] bf16
    const unsigned short* __restrict__ wb,  // [3,3,H,H] bf16 (W[o][h])
    const float* __restrict__ be,           // [3,3,H] fp32
    const int* __restrict__ perm, const float* __restrict__ scale,
    const int* __restrict__ counts,
    float* __restrict__ out,                // [B,3,S,H] fp32
    int T) {
  int z = blockIdx.z;           // r*3+e
  int r = z / 3;
  int count = counts[z];
  int m0 = blockIdx.x * 256;
  if (m0 >= count) return;
  int n0 = blockIdx.y * 256;

  __shared__ alignas(16) unsigned short As[3][256 * 32];  // 3 x 16KB
  __shared__ alignas(16) unsigned short Bs[3][256 * 32];  // 3 x 16KB
  __shared__ int toks[256];
  __shared__ float scl[256];
  __shared__ float bias_s[256];

  int tid = threadIdx.x;
  int lane = tid & 63;
  int w = tid >> 6;     // wave 0..7

  if (tid < 256) {
    int row = m0 + tid;
    int grow = row < count ? row : count - 1;  // clamp (valid addr, store-guarded)
    int tok = perm[(size_t)z * T + grow];
    toks[tid] = tok;
    scl[tid] = (row < count) ? scale[(size_t)r * T + tok] : 0.0f;
    bias_s[tid] = be[(size_t)z * HH + n0 + tid];
  }
  __syncthreads();  // toks ready; also drains vmcnt -> pipeline counter at 0

  // staging: wave w stages rows [w*32, w*32+32) of both A and B tiles.
  // GLDS is linear (base + lane*16): lane l -> row base+(l>>2), 16B slot l&3.
  // Rotation swizzle: LDS slot j of row holds global segment j ^ (row&3),
  // applied by pre-rotating the per-lane GLOBAL source offset (rule 21).
  size_t aoff[2], boff[2];
  int sseg = ((lane & 3) ^ ((lane >> 2) & 3));  // (row&3) == (lane>>2)&3
#pragma unroll
  for (int c = 0; c < 2; ++c) {
    int rowl = w * 32 + c * 16 + (lane >> 2);
    int tok = toks[rowl];
    aoff[c] = (size_t)(r * T + tok) * HH + sseg * 8;
    boff[c] = ((size_t)z * HH + n0 + rowl) * HH + sseg * 8;  // W[n][h]
  }

  int wr = w >> 2;        // 0..1 -> m-offset wr*128
  int wc = w & 3;         // 0..3 -> n-offset wc*64
  int wm = wr * 128;
  int wn = wc * 64;
  floatx4 acc[8][4] = {};

  // read side: frag row rr_ = base + (lane&15); logical 16B slot q = lane>>4;
  // physical slot = q ^ (rr_&3) = q ^ (rl&3) (bases are multiples of 16).
  // 64 lanes -> 8 (row-parity, slot) buckets x 4 banks = 8 dwords/bank: optimal.
  int rl = lane & 15;
  int rslot = (((lane >> 4) ^ (rl & 3))) * 8;  // element offset within row

  auto STAGE = [&](int kt) {
    int b_ = kt % 3;
    int kk_ = kt * 32;
    GLDS(xb + aoff[0] + kk_, &As[b_][(w * 32 + 0) * 32]);
    GLDS(wb + boff[0] + kk_, &Bs[b_][(w * 32 + 0) * 32]);
    GLDS(xb + aoff[1] + kk_, &As[b_][(w * 32 + 16) * 32]);
    GLDS(wb + boff[1] + kk_, &Bs[b_][(w * 32 + 16) * 32]);
  };
  auto COMPUTE = [&](int kt) {
    int b_ = kt % 3;
    bf16x8 af[8], bq[4];
#pragma unroll
    for (int mt = 0; mt < 8; ++mt)
      af[mt] = *reinterpret_cast<const bf16x8*>(
          &As[b_][(wm + mt * 16 + rl) * 32 + rslot]);
#pragma unroll
    for (int nt = 0; nt < 4; ++nt)
      bq[nt] = *reinterpret_cast<const bf16x8*>(
          &Bs[b_][(wn + nt * 16 + rl) * 32 + rslot]);
    __builtin_amdgcn_s_setprio(1);
#pragma unroll
    for (int mt = 0; mt < 8; ++mt)
#pragma unroll
      for (int nt = 0; nt < 4; ++nt)
        acc[mt][nt] = __builtin_amdgcn_mfma_f32_16x16x32_bf16(
            af[mt], bq[nt], acc[mt][nt], 0, 0, 0);
    __builtin_amdgcn_s_setprio(0);
  };

  STAGE(0);
  STAGE(1);
  // main loop: 32 K-steps (HH/32). Peel the last (full drain there only).
  for (int kt = 0; kt < 31; ++kt) {
    // counted wait + barrier in ONE asm so nothing schedules between.
    asm volatile("s_waitcnt vmcnt(4)\n\ts_barrier" ::: "memory");
    if (kt < 30) STAGE(kt + 2);
    COMPUTE(kt);
  }
  asm volatile("s_waitcnt vmcnt(0)\n\ts_barrier" ::: "memory");
  COMPUTE(31);

  // epilogue: D row = (lane>>4)*4+reg, col = lane&15 (verified layout)
#pragma unroll
  for (int mt = 0; mt < 8; ++mt) {
#pragma unroll
    for (int rr = 0; rr < 4; ++rr) {
      int ml = wm + mt * 16 + (lane >> 4) * 4 + rr;
      if (m0 + ml < count) {
        float sc = scl[ml];
        int tok = toks[ml];
        size_t ob =
            (size_t)(((tok >> 10) * 3 + r) * SS + (tok & 1023)) * HH + n0;
#pragma unroll
        for (int nt = 0; nt < 4; ++nt) {
          int nl = wn + nt * 16 + rl;
          out[ob + nl] = sc * (acc[mt][nt][rr] + bias_s[nl]);
        }
      }
    }
  }
}

extern "C" void kernel_launch(void* const* d_in, const int* in_sizes, int n_in,
                              void* d_out, int out_size, void* d_ws,
                              size_t ws_size, hipStream_t stream) {
  const float* feat = (const float*)d_in[0];  // features fp32
  const float* gw   = (const float*)d_in[1];  // gate_w fp32
  const float* ew   = (const float*)d_in[2];  // expert_w fp32
  const float* eb   = (const float*)d_in[3];  // expert_b fp32
  float* out = (float*)d_out;

  int B = in_sizes[0] / (3 * SS * HH);
  int T = B * SS;                  // tokens per branch (8192)
  int C = (T + EE - 1) / EE;       // capacity = ceil(T/E) = 2731

  // workspace layout: xb bf16 [3,T,H] | wb bf16 [9,H,H] | ints/floats (~70 MB)
  unsigned short* xbuf = (unsigned short*)d_ws;           // 3*T*HH shorts
  unsigned short* wbuf = xbuf + (size_t)3 * T * HH;       // 9*HH*HH shorts
  int* perm   = (int*)(wbuf + (size_t)9 * HH * HH);       // 9*T
  int* counts = perm + (size_t)9 * T;                     // 16 (padded)
  int* idxb   = counts + 16;                              // 3*T
  float* gv   = (float*)(idxb + (size_t)3 * T);           // 3*T
  float* scl  = gv + (size_t)3 * T;                       // 3*T

  int n8 = 9 * HH * HH / 8;
  k_route<<<dim3(1536), dim3(256), 0, stream>>>(feat, gw, xbuf, idxb, gv, T);
  k_scanconv<<<dim3(3 + n8 / 1024), dim3(1024), 0, stream>>>(
      idxb, gv, ew, wbuf, perm, scl, counts, T, C, n8);
  k_gemm<<<dim3((T + 255) / 256, HH / 256, 9), dim3(512), 0, stream>>>(
      xbuf, wbuf, eb, perm, scl, counts, out, T);
}

// Round 3
// 322.158 us; speedup vs baseline: 1.3127x; 1.3127x over previous
//
#include <hip/hip_runtime.h>
#include <math.h>

#define HH 1024
#define SS 1024
#define EE 3

typedef __bf16 bf16x8 __attribute__((ext_vector_type(8)));
typedef float floatx4 __attribute__((ext_vector_type(4)));

__device__ __forceinline__ unsigned short f2bf(float f) {
  union { float f; unsigned u; } v; v.f = f;
  unsigned r = 0x7FFFu + ((v.u >> 16) & 1u);
  return (unsigned short)((v.u + r) >> 16);
}
__device__ __forceinline__ unsigned pack2(float lo, float hi) {
#if __has_builtin(__builtin_amdgcn_cvt_pk_bf16_f32)
  auto p = __builtin_amdgcn_cvt_pk_bf16_f32(lo, hi);
  return __builtin_bit_cast(unsigned, p);
#else
  return ((unsigned)f2bf(hi) << 16) | (unsigned)f2bf(lo);
#endif
}

#define GLDS(gp, lp)                                                    \
  __builtin_amdgcn_global_load_lds(                                     \
      (const __attribute__((address_space(1))) void*)(const void*)(gp), \
      (__attribute__((address_space(3))) void*)(void*)(lp), 16, 0, 0)

// ---------- kernel 1: routing (argmax + gate) fused with x -> bf16 ----------
__global__ __launch_bounds__(256) void k_route(
    const float* __restrict__ x,          // [B,3,S,H] fp32
    const float* __restrict__ wg,         // [3,H,3]   fp32
    unsigned short* __restrict__ xb,      // [3,T,H] bf16 out
    int* __restrict__ idx_out,            // [3*T]
    float* __restrict__ gv_out,           // [3*T]
    int T) {
  int gw = (blockIdx.x * 256 + threadIdx.x) >> 6;  // global wave id [0,6144)
  int lane = threadIdx.x & 63;
  int r = gw >> 11;          // branch [0,3)
  int t0 = gw & 2047;        // starting token
  const float* w = wg + (size_t)r * HH * EE;

  // hoist this lane's gate slice: chunks c=0,1; h0 = c*512 + lane*8
  float wreg[2][24];
#pragma unroll
  for (int c = 0; c < 2; ++c) {
    int h0 = c * 512 + lane * 8;
    const float4* wp = reinterpret_cast<const float4*>(w + (size_t)h0 * 3);
#pragma unroll
    for (int j = 0; j < 6; ++j)
      *reinterpret_cast<float4*>(&wreg[c][4 * j]) = wp[j];
  }

  for (int t = t0; t < T; t += 2048) {
    const float* xrow =
        x + (size_t)(((t >> 10) * 3 + r) * SS + (t & 1023)) * HH;
    unsigned short* xbrow = xb + (size_t)(r * T + t) * HH;
    double a0 = 0, a1 = 0, a2 = 0;
#pragma unroll
    for (int c = 0; c < 2; ++c) {
      int h0 = c * 512 + lane * 8;
      float4 xa = *reinterpret_cast<const float4*>(xrow + h0);
      float4 xb4 = *reinterpret_cast<const float4*>(xrow + h0 + 4);
      float xs[8] = {xa.x, xa.y, xa.z, xa.w, xb4.x, xb4.y, xb4.z, xb4.w};
      // fused bf16 write-out (RNE, same as GEMM previously used)
      uint4 pk;
      pk.x = pack2(xs[0], xs[1]); pk.y = pack2(xs[2], xs[3]);
      pk.z = pack2(xs[4], xs[5]); pk.w = pack2(xs[6], xs[7]);
      *reinterpret_cast<uint4*>(xbrow + h0) = pk;
#pragma unroll
      for (int j = 0; j < 8; ++j) {
        double xv = (double)xs[j];
        a0 += xv * (double)wreg[c][3 * j + 0];
        a1 += xv * (double)wreg[c][3 * j + 1];
        a2 += xv * (double)wreg[c][3 * j + 2];
      }
    }
#pragma unroll
    for (int d = 32; d >= 1; d >>= 1) {
      a0 += __shfl_xor(a0, d, 64);
      a1 += __shfl_xor(a1, d, 64);
      a2 += __shfl_xor(a2, d, 64);
    }
    if (lane == 0) {
      int best = 0; double bl = a0;
      if (a1 > bl) { best = 1; bl = a1; }  // strict >: first-max wins
      if (a2 > bl) { best = 2; bl = a2; }
      float g = 1.0f / (expf((float)(a0 - bl)) + expf((float)(a1 - bl)) +
                        expf((float)(a2 - bl)));
      idx_out[r * T + t] = best;
      gv_out[r * T + t] = g;
    }
  }
}

// ------- kernel 2: arrival-order scan (3 blocks) + We fp32->bf16 (rest) -------
__global__ __launch_bounds__(1024) void k_scanconv(
    const int* __restrict__ idx, const float* __restrict__ gv,
    const float* __restrict__ We, unsigned short* __restrict__ wb,
    int* __restrict__ perm,    // [3*3*T] token ids per (branch,expert)
    float* __restrict__ scale, // [3*T]  gate*keep (0 if dropped)
    int* __restrict__ counts,  // [9]
    int T, int C, int n8) {
  if (blockIdx.x >= 3) {
    // ---- convw part: one 8-elem segment per thread ----
    int i = (blockIdx.x - 3) * 1024 + threadIdx.x;
    if (i < n8) {
      const float4* p = reinterpret_cast<const float4*>(We + (size_t)i * 8);
      float4 a = p[0], b = p[1];
      uint4 pk;
      pk.x = pack2(a.x, a.y); pk.y = pack2(a.z, a.w);
      pk.z = pack2(b.x, b.y); pk.w = pack2(b.z, b.w);
      *reinterpret_cast<uint4*>(wb + (size_t)i * 8) = pk;
    }
    return;
  }
  // ---- scan part (blocks 0..2), unchanged logic ----
  int r = blockIdx.x;
  int tid = threadIdx.x;
  int per = T >> 10;  // tokens per thread (T=8192 -> 8)
  int t0 = tid * per;
  const int* idxr = idx + (size_t)r * T;

  int c0 = 0, c1 = 0, c2 = 0;
  for (int k = 0; k < per; ++k) {
    int e = idxr[t0 + k];
    c0 += (e == 0); c1 += (e == 1); c2 += (e == 2);
  }
  int lane = tid & 63, wv = tid >> 6;
  int s0 = c0, s1 = c1, s2 = c2;  // wave inclusive scan
  for (int d = 1; d < 64; d <<= 1) {
    int u0 = __shfl_up(s0, d, 64);
    int u1 = __shfl_up(s1, d, 64);
    int u2 = __shfl_up(s2, d, 64);
    if (lane >= d) { s0 += u0; s1 += u1; s2 += u2; }
  }
  __shared__ int wsum[16][3];
  __shared__ int wbase[16][3];
  if (lane == 63) { wsum[wv][0] = s0; wsum[wv][1] = s1; wsum[wv][2] = s2; }
  __syncthreads();
  if (tid == 0) {
    int b0 = 0, b1 = 0, b2 = 0;
    int nw = blockDim.x >> 6;
    for (int i = 0; i < nw; ++i) {
      wbase[i][0] = b0; wbase[i][1] = b1; wbase[i][2] = b2;
      b0 += wsum[i][0]; b1 += wsum[i][1]; b2 += wsum[i][2];
    }
    counts[r * 3 + 0] = b0; counts[r * 3 + 1] = b1; counts[r * 3 + 2] = b2;
  }
  __syncthreads();
  int off[3];
  off[0] = wbase[wv][0] + s0 - c0;
  off[1] = wbase[wv][1] + s1 - c1;
  off[2] = wbase[wv][2] + s2 - c2;
  for (int k = 0; k < per; ++k) {
    int e = idxr[t0 + k];
    int p = off[e]++;
    perm[(size_t)(r * 3 + e) * T + p] = t0 + k;
    scale[(size_t)r * T + t0 + k] = (p < C) ? gv[(size_t)r * T + t0 + k] : 0.0f;
  }
}

// -------- kernel 3: grouped GEMM, BM=128 BN=256 BK=32, 4 waves --------
// Per-wave output 128x64 (acc[8][4]): 32 MFMA per 12 ds_read_b128 =
// 42.7 FLOP/LDS-byte (1.33x the old 4x4 config). 4-wave block keeps the
// ~228-unified-reg wave footprint compatible with 2 waves/SIMD -> 2 blocks/CU
// (round-2's 8-wave block could not co-reside). Triple-buffered LDS (74 KB),
// distance-2 counted vmcnt(6) fused with one raw s_barrier per K-step
// (round-1-verified schedule), round-1-verified rotation swizzle (0 conflicts).
//
// Race proof (6 GLDS per STAGE): at iter kt's wait, vmcnt(6) allows only
// STAGE(kt+1)'s 6 loads outstanding -> STAGE(kt) landed; barrier -> all
// waves' shares landed. STAGE(kt+2) overwrites slot (kt+2)%3 = (kt-1)%3,
// whose ds_reads retired before each wave reached THIS barrier.
__global__ __launch_bounds__(256, 2) void k_gemm(
    const unsigned short* __restrict__ xb,  // [3,T,H] bf16
    const unsigned short* __restrict__ wb,  // [3,3,H,H] bf16 (W[o][h])
    const float* __restrict__ be,           // [3,3,H] fp32
    const int* __restrict__ perm, const float* __restrict__ scale,
    const int* __restrict__ counts,
    float* __restrict__ out,                // [B,3,S,H] fp32
    int T) {
  int z = blockIdx.z;           // r*3+e
  int r = z / 3;
  int count = counts[z];
  int m0 = blockIdx.x * 128;
  if (m0 >= count) return;
  int n0 = blockIdx.y * 256;

  __shared__ alignas(16) unsigned short As[3][128 * 32];  // 3 x 8KB
  __shared__ alignas(16) unsigned short Bs[3][256 * 32];  // 3 x 16KB
  __shared__ int toks[128];
  __shared__ float scl[128];
  __shared__ float bias_s[256];

  int tid = threadIdx.x;
  int lane = tid & 63;
  int w = tid >> 6;     // wave 0..3

  if (tid < 128) {
    int row = m0 + tid;
    int grow = row < count ? row : count - 1;  // clamp (valid addr, store-guarded)
    int tok = perm[(size_t)z * T + grow];
    toks[tid] = tok;
    scl[tid] = (row < count) ? scale[(size_t)r * T + tok] : 0.0f;
  }
  bias_s[tid] = be[(size_t)z * HH + n0 + tid];  // 256 cols
  __syncthreads();  // toks ready; also drains vmcnt -> pipeline counter at 0

  // staging: GLDS is linear (base + lane*16): lane l -> row base+(l>>2),
  // 16B slot l&3. Rotation swizzle (round-1-verified, 0 conflicts): LDS slot
  // j of row holds global segment (j - ((row>>1)&3))&3, applied by
  // pre-rotating the per-lane GLOBAL source offset (rule 21).
  // A tile 128 rows: 2 groups/wave; B tile 256 rows: 4 groups/wave.
  size_t aoff[2], boff[4];
  int sseg = ((lane & 3) - ((lane >> 3) & 3)) & 3;  // (l>>3)&3 == ((row&15)>>1)&3
#pragma unroll
  for (int c = 0; c < 2; ++c) {
    int rowl = w * 32 + c * 16 + (lane >> 2);
    int tok = toks[rowl];
    aoff[c] = (size_t)(r * T + tok) * HH + sseg * 8;
  }
#pragma unroll
  for (int c = 0; c < 4; ++c) {
    int rowl = w * 64 + c * 16 + (lane >> 2);
    boff[c] = ((size_t)z * HH + n0 + rowl) * HH + sseg * 8;  // W[n][h]
  }

  int wn = w * 64;      // per-wave N-slice; M-slice = full 128 rows
  floatx4 acc[8][4] = {};

  // read side: frag row = base16 + rl; slot = (q + ((rl>>1)&3))&3, q=lane>>4.
  // 64 lanes -> 8 (row-parity, slot) 16B-groups x 8 lanes = 2 lanes/bank: free.
  int rl = lane & 15;
  int rslot = (((lane >> 4) + ((rl >> 1) & 3)) & 3) * 8;  // elem offset in row

  auto STAGE = [&](int kt) {
    int b_ = kt % 3;
    int kk_ = kt * 32;
    GLDS(xb + aoff[0] + kk_, &As[b_][(w * 32 + 0) * 32]);
    GLDS(xb + aoff[1] + kk_, &As[b_][(w * 32 + 16) * 32]);
    GLDS(wb + boff[0] + kk_, &Bs[b_][(w * 64 + 0) * 32]);
    GLDS(wb + boff[1] + kk_, &Bs[b_][(w * 64 + 16) * 32]);
    GLDS(wb + boff[2] + kk_, &Bs[b_][(w * 64 + 32) * 32]);
    GLDS(wb + boff[3] + kk_, &Bs[b_][(w * 64 + 48) * 32]);
  };
  auto COMPUTE = [&](int kt) {
    int b_ = kt % 3;
    bf16x8 af[8], bq[4];
#pragma unroll
    for (int mt = 0; mt < 8; ++mt)
      af[mt] = *reinterpret_cast<const bf16x8*>(
          &As[b_][(mt * 16 + rl) * 32 + rslot]);
#pragma unroll
    for (int nt = 0; nt < 4; ++nt)
      bq[nt] = *reinterpret_cast<const bf16x8*>(
          &Bs[b_][(wn + nt * 16 + rl) * 32 + rslot]);
    __builtin_amdgcn_s_setprio(1);
#pragma unroll
    for (int mt = 0; mt < 8; ++mt)
#pragma unroll
      for (int nt = 0; nt < 4; ++nt)
        acc[mt][nt] = __builtin_amdgcn_mfma_f32_16x16x32_bf16(
            af[mt], bq[nt], acc[mt][nt], 0, 0, 0);
    __builtin_amdgcn_s_setprio(0);
  };

  STAGE(0);
  STAGE(1);
  // main loop: 32 K-steps (HH/32). Peel the last (full drain there only).
  for (int kt = 0; kt < 31; ++kt) {
    // counted wait + barrier in ONE asm so nothing schedules between.
    asm volatile("s_waitcnt vmcnt(6)\n\ts_barrier" ::: "memory");
    if (kt < 30) STAGE(kt + 2);
    COMPUTE(kt);
  }
  asm volatile("s_waitcnt vmcnt(0)\n\ts_barrier" ::: "memory");
  COMPUTE(31);

  // epilogue: D row = (lane>>4)*4+reg, col = lane&15 (verified layout)
#pragma unroll
  for (int mt = 0; mt < 8; ++mt) {
#pragma unroll
    for (int rr = 0; rr < 4; ++rr) {
      int ml = mt * 16 + (lane >> 4) * 4 + rr;
      if (m0 + ml < count) {
        float sc = scl[ml];
        int tok = toks[ml];
        size_t ob =
            (size_t)(((tok >> 10) * 3 + r) * SS + (tok & 1023)) * HH + n0;
#pragma unroll
        for (int nt = 0; nt < 4; ++nt) {
          int nl = wn + nt * 16 + rl;
          out[ob + nl] = sc * (acc[mt][nt][rr] + bias_s[nl]);
        }
      }
    }
  }
}

extern "C" void kernel_launch(void* const* d_in, const int* in_sizes, int n_in,
                              void* d_out, int out_size, void* d_ws,
                              size_t ws_size, hipStream_t stream) {
  const float* feat = (const float*)d_in[0];  // features fp32
  const float* gw   = (const float*)d_in[1];  // gate_w fp32
  const float* ew   = (const float*)d_in[2];  // expert_w fp32
  const float* eb   = (const float*)d_in[3];  // expert_b fp32
  float* out = (float*)d_out;

  int B = in_sizes[0] / (3 * SS * HH);
  int T = B * SS;                  // tokens per branch (8192)
  int C = (T + EE - 1) / EE;       // capacity = ceil(T/E) = 2731

  // workspace layout: xb bf16 [3,T,H] | wb bf16 [9,H,H] | ints/floats (~70 MB)
  unsigned short* xbuf = (unsigned short*)d_ws;           // 3*T*HH shorts
  unsigned short* wbuf = xbuf + (size_t)3 * T * HH;       // 9*HH*HH shorts
  int* perm   = (int*)(wbuf + (size_t)9 * HH * HH);       // 9*T
  int* counts = perm + (size_t)9 * T;                     // 16 (padded)
  int* idxb   = counts + 16;                              // 3*T
  float* gv   = (float*)(idxb + (size_t)3 * T);           // 3*T
  float* scl  = gv + (size_t)3 * T;                       // 3*T

  int n8 = 9 * HH * HH / 8;
  k_route<<<dim3(1536), dim3(256), 0, stream>>>(feat, gw, xbuf, idxb, gv, T);
  k_scanconv<<<dim3(3 + n8 / 1024), dim3(1024), 0, stream>>>(
      idxb, gv, ew, wbuf, perm, scl, counts, T, C, n8);
  k_gemm<<<dim3((T + 127) / 128, HH / 256, 9), dim3(256), 0, stream>>>(
      xbuf, wbuf, eb, perm, scl, counts, out, T);
}

// Round 4
// 305.958 us; speedup vs baseline: 1.3822x; 1.0529x over previous
//
#include <hip/hip_runtime.h>
#include <math.h>

#define HH 1024
#define SS 1024
#define EE 3

typedef __bf16 bf16x8 __attribute__((ext_vector_type(8)));
typedef float floatx4 __attribute__((ext_vector_type(4)));

__device__ __forceinline__ unsigned short f2bf(float f) {
  union { float f; unsigned u; } v; v.f = f;
  unsigned r = 0x7FFFu + ((v.u >> 16) & 1u);
  return (unsigned short)((v.u + r) >> 16);
}
__device__ __forceinline__ unsigned pack2(float lo, float hi) {
#if __has_builtin(__builtin_amdgcn_cvt_pk_bf16_f32)
  auto p = __builtin_amdgcn_cvt_pk_bf16_f32(lo, hi);
  return __builtin_bit_cast(unsigned, p);
#else
  return ((unsigned)f2bf(hi) << 16) | (unsigned)f2bf(lo);
#endif
}

#define GLDS(gp, lp)                                                    \
  __builtin_amdgcn_global_load_lds(                                     \
      (const __attribute__((address_space(1))) void*)(const void*)(gp), \
      (__attribute__((address_space(3))) void*)(void*)(lp), 16, 0, 0)

// ---- kernel 1: routing (argmax + gate) fused with x -> bf16, plus We ----
// ---- fp32->bf16 conversion riding along in blocks >= 1536 (independent) ----
__global__ __launch_bounds__(256) void k_route(
    const float* __restrict__ x,          // [B,3,S,H] fp32
    const float* __restrict__ wg,         // [3,H,3]   fp32
    const float* __restrict__ We,         // [3,E,H,H] fp32
    unsigned short* __restrict__ xb,      // [3,T,H] bf16 out
    unsigned short* __restrict__ wbuf,    // [9,H,H] bf16 out
    int* __restrict__ idx_out,            // [3*T]
    float* __restrict__ gv_out,           // [3*T]
    int T) {
  if (blockIdx.x >= 1536) {
    // ---- convw part: 1152 blocks x 256 threads x 4 segments of 8 elems ----
    int b = blockIdx.x - 1536;
    int base = b * 1024 + threadIdx.x;
#pragma unroll
    for (int k = 0; k < 4; ++k) {
      int i = base + k * 256;  // < 1152*1024 = 9*HH*HH/8 exactly
      const float4* p = reinterpret_cast<const float4*>(We + (size_t)i * 8);
      float4 a = p[0], bv = p[1];
      uint4 pk;
      pk.x = pack2(a.x, a.y);  pk.y = pack2(a.z, a.w);
      pk.z = pack2(bv.x, bv.y); pk.w = pack2(bv.z, bv.w);
      *reinterpret_cast<uint4*>(wbuf + (size_t)i * 8) = pk;
    }
    return;
  }
  int gw = (blockIdx.x * 256 + threadIdx.x) >> 6;  // global wave id [0,6144)
  int lane = threadIdx.x & 63;
  int r = gw >> 11;          // branch [0,3)
  int t0 = gw & 2047;        // starting token
  const float* w = wg + (size_t)r * HH * EE;

  // hoist this lane's gate slice: chunks c=0,1; h0 = c*512 + lane*8
  float wreg[2][24];
#pragma unroll
  for (int c = 0; c < 2; ++c) {
    int h0 = c * 512 + lane * 8;
    const float4* wp = reinterpret_cast<const float4*>(w + (size_t)h0 * 3);
#pragma unroll
    for (int j = 0; j < 6; ++j)
      *reinterpret_cast<float4*>(&wreg[c][4 * j]) = wp[j];
  }

  for (int t = t0; t < T; t += 2048) {
    const float* xrow =
        x + (size_t)(((t >> 10) * 3 + r) * SS + (t & 1023)) * HH;
    unsigned short* xbrow = xb + (size_t)(r * T + t) * HH;
    double a0 = 0, a1 = 0, a2 = 0;
#pragma unroll
    for (int c = 0; c < 2; ++c) {
      int h0 = c * 512 + lane * 8;
      float4 xa = *reinterpret_cast<const float4*>(xrow + h0);
      float4 xb4 = *reinterpret_cast<const float4*>(xrow + h0 + 4);
      float xs[8] = {xa.x, xa.y, xa.z, xa.w, xb4.x, xb4.y, xb4.z, xb4.w};
      // fused bf16 write-out (RNE, same as GEMM previously used)
      uint4 pk;
      pk.x = pack2(xs[0], xs[1]); pk.y = pack2(xs[2], xs[3]);
      pk.z = pack2(xs[4], xs[5]); pk.w = pack2(xs[6], xs[7]);
      *reinterpret_cast<uint4*>(xbrow + h0) = pk;
#pragma unroll
      for (int j = 0; j < 8; ++j) {
        double xv = (double)xs[j];
        a0 += xv * (double)wreg[c][3 * j + 0];
        a1 += xv * (double)wreg[c][3 * j + 1];
        a2 += xv * (double)wreg[c][3 * j + 2];
      }
    }
#pragma unroll
    for (int d = 32; d >= 1; d >>= 1) {
      a0 += __shfl_xor(a0, d, 64);
      a1 += __shfl_xor(a1, d, 64);
      a2 += __shfl_xor(a2, d, 64);
    }
    if (lane == 0) {
      int best = 0; double bl = a0;
      if (a1 > bl) { best = 1; bl = a1; }  // strict >: first-max wins
      if (a2 > bl) { best = 2; bl = a2; }
      float g = 1.0f / (expf((float)(a0 - bl)) + expf((float)(a1 - bl)) +
                        expf((float)(a2 - bl)));
      idx_out[r * T + t] = best;
      gv_out[r * T + t] = g;
    }
  }
}

// ---------------- kernel 2: arrival-order scan + expert lists ----------------
__global__ __launch_bounds__(1024) void k_scan(
    const int* __restrict__ idx, const float* __restrict__ gv,
    int* __restrict__ perm,    // [3*3*T] token ids per (branch,expert)
    float* __restrict__ scale, // [3*T]  gate*keep (0 if dropped)
    int* __restrict__ counts,  // [9]
    int T, int C) {
  int r = blockIdx.x;
  int tid = threadIdx.x;
  int per = T >> 10;  // tokens per thread (T=8192 -> 8)
  int t0 = tid * per;
  const int* idxr = idx + (size_t)r * T;

  int c0 = 0, c1 = 0, c2 = 0;
  for (int k = 0; k < per; ++k) {
    int e = idxr[t0 + k];
    c0 += (e == 0); c1 += (e == 1); c2 += (e == 2);
  }
  int lane = tid & 63, wv = tid >> 6;
  int s0 = c0, s1 = c1, s2 = c2;  // wave inclusive scan
  for (int d = 1; d < 64; d <<= 1) {
    int u0 = __shfl_up(s0, d, 64);
    int u1 = __shfl_up(s1, d, 64);
    int u2 = __shfl_up(s2, d, 64);
    if (lane >= d) { s0 += u0; s1 += u1; s2 += u2; }
  }
  __shared__ int wsum[16][3];
  __shared__ int wbase[16][3];
  if (lane == 63) { wsum[wv][0] = s0; wsum[wv][1] = s1; wsum[wv][2] = s2; }
  __syncthreads();
  if (tid == 0) {
    int b0 = 0, b1 = 0, b2 = 0;
    int nw = blockDim.x >> 6;
    for (int i = 0; i < nw; ++i) {
      wbase[i][0] = b0; wbase[i][1] = b1; wbase[i][2] = b2;
      b0 += wsum[i][0]; b1 += wsum[i][1]; b2 += wsum[i][2];
    }
    counts[r * 3 + 0] = b0; counts[r * 3 + 1] = b1; counts[r * 3 + 2] = b2;
  }
  __syncthreads();
  int off[3];
  off[0] = wbase[wv][0] + s0 - c0;
  off[1] = wbase[wv][1] + s1 - c1;
  off[2] = wbase[wv][2] + s2 - c2;
  for (int k = 0; k < per; ++k) {
    int e = idxr[t0 + k];
    int p = off[e]++;
    perm[(size_t)(r * 3 + e) * T + p] = t0 + k;
    scale[(size_t)r * T + t0 + k] = (p < C) ? gv[(size_t)r * T + t0 + k] : 0.0f;
  }
}

// -------- kernel 3: grouped GEMM, round-1 geometry + XCD-aware swizzle --------
// 128x128 tile, BK=32, 4 waves, 3 blocks/CU (49.5KB LDS, 132 unified regs).
// Triple-buffered LDS, counted s_waitcnt vmcnt(4) fused with one raw s_barrier
// per K-step (verified round 1: 0 bank conflicts, correct), rotation swizzle.
//
// NEW: 1D grid, bijective XCD chunking (nwg = 4608 = 8 x 576 exactly).
// Logical order (z, x, y-fastest): the 8 n-sibling blocks that share one
// gathered A panel are CONSECUTIVE logicals -> same XCD -> A panel is fetched
// once into that XCD's L2 and re-read 7x as L2 hits (previously each sibling
// landed on a different XCD and re-fetched from L3/HBM). Each XCD's 576-chunk
// also covers ~one expert, keeping its 2MB weight panel L2-resident.
__global__ __launch_bounds__(256, 3) void k_gemm(
    const unsigned short* __restrict__ xb,  // [3,T,H] bf16
    const unsigned short* __restrict__ wb,  // [3,3,H,H] bf16 (W[o][h])
    const float* __restrict__ be,           // [3,3,H] fp32
    const int* __restrict__ perm, const float* __restrict__ scale,
    const int* __restrict__ counts,
    float* __restrict__ out,                // [B,3,S,H] fp32
    int T) {
  // XCD swizzle: consecutive hardware block ids round-robin the 8 XCDs;
  // give XCD (p&7) the contiguous logical range [(p&7)*576, ...+576).
  int p = blockIdx.x;                 // 0..4607
  int wg = (p & 7) * 576 + (p >> 3);  // bijective: 4608 = 8*576
  int z = wg >> 9;                    // 0..8  (branch*3 + expert)
  int x = (wg >> 3) & 63;             // m-block
  int y = wg & 7;                     // n-block (fastest -> A-sharing siblings)

  int r = z / 3;
  int count = counts[z];
  int m0 = x * 128;
  if (m0 >= count) return;
  int n0 = y * 128;

  __shared__ alignas(16) unsigned short As[3][128 * 32];
  __shared__ alignas(16) unsigned short Bs[3][128 * 32];
  __shared__ int toks[128];
  __shared__ float scl[128];
  __shared__ float bias_s[128];

  int tid = threadIdx.x;
  int lane = tid & 63;
  int w = tid >> 6;

  if (tid < 128) {
    int row = m0 + tid;
    int grow = row < count ? row : count - 1;  // clamp (valid addr, store-guarded)
    int tok = perm[(size_t)z * T + grow];
    toks[tid] = tok;
    scl[tid] = (row < count) ? scale[(size_t)r * T + tok] : 0.0f;
    bias_s[tid] = be[(size_t)z * HH + n0 + tid];
  }
  __syncthreads();  // toks ready; also drains vmcnt -> pipeline counter at 0

  // staging: GLDS is linear (base + lane*16): lane l -> row base+(l>>2),
  // 16B slot l&3. Rotation swizzle (verified 0 conflicts): LDS slot j of row
  // holds global segment (j - ((row>>1)&3))&3, applied by pre-rotating the
  // per-lane GLOBAL source offset (rule 21).
  size_t aoff[2], boff[2];
  int sseg = ((lane & 3) - ((lane >> 3) & 3)) & 3;  // (l>>3)&3 == ((row&15)>>1)&3
#pragma unroll
  for (int c = 0; c < 2; ++c) {
    int rowl = w * 32 + c * 16 + (lane >> 2);
    int tok = toks[rowl];
    aoff[c] = (size_t)(r * T + tok) * HH + sseg * 8;
    boff[c] = ((size_t)z * HH + n0 + rowl) * HH + sseg * 8;  // W[n][h]
  }

  int wm = (w >> 1) * 64;
  int wn = (w & 1) * 64;
  floatx4 acc[4][4] = {};

  // read side: frag row = base16 + rl; slot = (q + ((rl>>1)&3))&3, q=lane>>4.
  // 64 lanes -> 8 (row-parity, slot) 16B-groups x 8 lanes = 2 lanes/bank: free.
  int rl = lane & 15;
  int rslot = ((lane >> 4) + ((rl >> 1) & 3)) & 3;

  auto STAGE = [&](int kt) {
    int b_ = kt % 3;
    int kk_ = kt * 32;
    GLDS(xb + aoff[0] + kk_, &As[b_][(w * 32 + 0) * 32]);
    GLDS(wb + boff[0] + kk_, &Bs[b_][(w * 32 + 0) * 32]);
    GLDS(xb + aoff[1] + kk_, &As[b_][(w * 32 + 16) * 32]);
    GLDS(wb + boff[1] + kk_, &Bs[b_][(w * 32 + 16) * 32]);
  };
  auto COMPUTE = [&](int kt) {
    int b_ = kt % 3;
    bf16x8 af[4], bq[4];
#pragma unroll
    for (int mt = 0; mt < 4; ++mt)
      af[mt] = *reinterpret_cast<const bf16x8*>(
          &As[b_][(wm + mt * 16 + rl) * 32 + rslot * 8]);
#pragma unroll
    for (int nt = 0; nt < 4; ++nt)
      bq[nt] = *reinterpret_cast<const bf16x8*>(
          &Bs[b_][(wn + nt * 16 + rl) * 32 + rslot * 8]);
    __builtin_amdgcn_s_setprio(1);
#pragma unroll
    for (int mt = 0; mt < 4; ++mt)
#pragma unroll
      for (int nt = 0; nt < 4; ++nt)
        acc[mt][nt] = __builtin_amdgcn_mfma_f32_16x16x32_bf16(
            af[mt], bq[nt], acc[mt][nt], 0, 0, 0);
    __builtin_amdgcn_s_setprio(0);
  };

  STAGE(0);
  STAGE(1);
  // main loop: 32 K-steps (HH/32). Peel the last (full drain there only).
  for (int kt = 0; kt < 31; ++kt) {
    // counted wait + barrier in ONE asm so nothing schedules between.
    asm volatile("s_waitcnt vmcnt(4)\n\ts_barrier" ::: "memory");
    if (kt < 30) STAGE(kt + 2);
    COMPUTE(kt);
  }
  asm volatile("s_waitcnt vmcnt(0)\n\ts_barrier" ::: "memory");
  COMPUTE(31);

  // epilogue: D row = (lane>>4)*4+reg, col = lane&15 (verified layout)
#pragma unroll
  for (int mt = 0; mt < 4; ++mt) {
#pragma unroll
    for (int rr = 0; rr < 4; ++rr) {
      int ml = wm + mt * 16 + (lane >> 4) * 4 + rr;
      if (m0 + ml < count) {
        float sc = scl[ml];
        int tok = toks[ml];
        size_t ob =
            (size_t)(((tok >> 10) * 3 + r) * SS + (tok & 1023)) * HH + n0;
#pragma unroll
        for (int nt = 0; nt < 4; ++nt) {
          int nl = wn + nt * 16 + rl;
          out[ob + nl] = sc * (acc[mt][nt][rr] + bias_s[nl]);
        }
      }
    }
  }
}

extern "C" void kernel_launch(void* const* d_in, const int* in_sizes, int n_in,
                              void* d_out, int out_size, void* d_ws,
                              size_t ws_size, hipStream_t stream) {
  const float* feat = (const float*)d_in[0];  // features fp32
  const float* gw   = (const float*)d_in[1];  // gate_w fp32
  const float* ew   = (const float*)d_in[2];  // expert_w fp32
  const float* eb   = (const float*)d_in[3];  // expert_b fp32
  float* out = (float*)d_out;

  int B = in_sizes[0] / (3 * SS * HH);
  int T = B * SS;                  // tokens per branch (8192)
  int C = (T + EE - 1) / EE;       // capacity = ceil(T/E) = 2731

  // workspace layout: xb bf16 [3,T,H] | wb bf16 [9,H,H] | ints/floats (~70 MB)
  unsigned short* xbuf = (unsigned short*)d_ws;           // 3*T*HH shorts
  unsigned short* wbuf = xbuf + (size_t)3 * T * HH;       // 9*HH*HH shorts
  int* perm   = (int*)(wbuf + (size_t)9 * HH * HH);       // 9*T
  int* counts = perm + (size_t)9 * T;                     // 16 (padded)
  int* idxb   = counts + 16;                              // 3*T
  float* gv   = (float*)(idxb + (size_t)3 * T);           // 3*T
  float* scl  = gv + (size_t)3 * T;                       // 3*T

  // route (1536 blocks) + weight conversion (1152 blocks) in one launch
  k_route<<<dim3(2688), dim3(256), 0, stream>>>(feat, gw, ew, xbuf, wbuf,
                                                idxb, gv, T);
  k_scan<<<dim3(3), dim3(1024), 0, stream>>>(idxb, gv, perm, scl, counts, T, C);
  k_gemm<<<dim3(4608), dim3(256), 0, stream>>>(
      xbuf, wbuf, eb, perm, scl, counts, out, T);
}

// Round 5
// 300.029 us; speedup vs baseline: 1.4095x; 1.0198x over previous
//
#include <hip/hip_runtime.h>
#include <math.h>

#define HH 1024
#define SS 1024
#define EE 3

typedef __bf16 bf16x8 __attribute__((ext_vector_type(8)));
typedef float floatx4 __attribute__((ext_vector_type(4)));

__device__ __forceinline__ unsigned short f2bf(float f) {
  union { float f; unsigned u; } v; v.f = f;
  unsigned r = 0x7FFFu + ((v.u >> 16) & 1u);
  return (unsigned short)((v.u + r) >> 16);
}
__device__ __forceinline__ unsigned pack2(float lo, float hi) {
#if __has_builtin(__builtin_amdgcn_cvt_pk_bf16_f32)
  auto p = __builtin_amdgcn_cvt_pk_bf16_f32(lo, hi);
  return __builtin_bit_cast(unsigned, p);
#else
  return ((unsigned)f2bf(hi) << 16) | (unsigned)f2bf(lo);
#endif
}

#define GLDS(gp, lp)                                                    \
  __builtin_amdgcn_global_load_lds(                                     \
      (const __attribute__((address_space(1))) void*)(const void*)(gp), \
      (__attribute__((address_space(3))) void*)(void*)(lp), 16, 0, 0)

// ---- kernel 1: routing (argmax + gate) fused with x -> bf16, plus We ----
// ---- fp32->bf16 conversion riding along in blocks >= 1536 (independent) ----
__global__ __launch_bounds__(256) void k_route(
    const float* __restrict__ x,          // [B,3,S,H] fp32
    const float* __restrict__ wg,         // [3,H,3]   fp32
    const float* __restrict__ We,         // [3,E,H,H] fp32
    unsigned short* __restrict__ xb,      // [3,T,H] bf16 out
    unsigned short* __restrict__ wbuf,    // [9,H,H] bf16 out
    int* __restrict__ idx_out,            // [3*T]
    float* __restrict__ gv_out,           // [3*T]
    int T) {
  if (blockIdx.x >= 1536) {
    // ---- convw part: 1152 blocks x 256 threads x 4 segments of 8 elems ----
    int b = blockIdx.x - 1536;
    int base = b * 1024 + threadIdx.x;
#pragma unroll
    for (int k = 0; k < 4; ++k) {
      int i = base + k * 256;  // < 1152*1024 = 9*HH*HH/8 exactly
      const float4* p = reinterpret_cast<const float4*>(We + (size_t)i * 8);
      float4 a = p[0], bv = p[1];
      uint4 pk;
      pk.x = pack2(a.x, a.y);  pk.y = pack2(a.z, a.w);
      pk.z = pack2(bv.x, bv.y); pk.w = pack2(bv.z, bv.w);
      *reinterpret_cast<uint4*>(wbuf + (size_t)i * 8) = pk;
    }
    return;
  }
  int gw = (blockIdx.x * 256 + threadIdx.x) >> 6;  // global wave id [0,6144)
  int lane = threadIdx.x & 63;
  int r = gw >> 11;          // branch [0,3)
  int t0 = gw & 2047;        // starting token
  const float* w = wg + (size_t)r * HH * EE;

  // hoist this lane's gate slice: chunks c=0,1; h0 = c*512 + lane*8
  float wreg[2][24];
#pragma unroll
  for (int c = 0; c < 2; ++c) {
    int h0 = c * 512 + lane * 8;
    const float4* wp = reinterpret_cast<const float4*>(w + (size_t)h0 * 3);
#pragma unroll
    for (int j = 0; j < 6; ++j)
      *reinterpret_cast<float4*>(&wreg[c][4 * j]) = wp[j];
  }

  for (int t = t0; t < T; t += 2048) {
    const float* xrow =
        x + (size_t)(((t >> 10) * 3 + r) * SS + (t & 1023)) * HH;
    unsigned short* xbrow = xb + (size_t)(r * T + t) * HH;
    double a0 = 0, a1 = 0, a2 = 0;
#pragma unroll
    for (int c = 0; c < 2; ++c) {
      int h0 = c * 512 + lane * 8;
      float4 xa = *reinterpret_cast<const float4*>(xrow + h0);
      float4 xb4 = *reinterpret_cast<const float4*>(xrow + h0 + 4);
      float xs[8] = {xa.x, xa.y, xa.z, xa.w, xb4.x, xb4.y, xb4.z, xb4.w};
      // fused bf16 write-out (RNE, same as GEMM previously used)
      uint4 pk;
      pk.x = pack2(xs[0], xs[1]); pk.y = pack2(xs[2], xs[3]);
      pk.z = pack2(xs[4], xs[5]); pk.w = pack2(xs[6], xs[7]);
      *reinterpret_cast<uint4*>(xbrow + h0) = pk;
#pragma unroll
      for (int j = 0; j < 8; ++j) {
        double xv = (double)xs[j];
        a0 += xv * (double)wreg[c][3 * j + 0];
        a1 += xv * (double)wreg[c][3 * j + 1];
        a2 += xv * (double)wreg[c][3 * j + 2];
      }
    }
#pragma unroll
    for (int d = 32; d >= 1; d >>= 1) {
      a0 += __shfl_xor(a0, d, 64);
      a1 += __shfl_xor(a1, d, 64);
      a2 += __shfl_xor(a2, d, 64);
    }
    if (lane == 0) {
      int best = 0; double bl = a0;
      if (a1 > bl) { best = 1; bl = a1; }  // strict >: first-max wins
      if (a2 > bl) { best = 2; bl = a2; }
      float g = 1.0f / (expf((float)(a0 - bl)) + expf((float)(a1 - bl)) +
                        expf((float)(a2 - bl)));
      idx_out[r * T + t] = best;
      gv_out[r * T + t] = g;
    }
  }
}

// ---------------- kernel 2: arrival-order scan + expert lists ----------------
__global__ __launch_bounds__(1024) void k_scan(
    const int* __restrict__ idx, const float* __restrict__ gv,
    int* __restrict__ perm,    // [3*3*T] token ids per (branch,expert)
    float* __restrict__ scale, // [3*T]  gate*keep (0 if dropped)
    int* __restrict__ counts,  // [9]
    int T, int C) {
  int r = blockIdx.x;
  int tid = threadIdx.x;
  int per = T >> 10;  // tokens per thread (T=8192 -> 8)
  int t0 = tid * per;
  const int* idxr = idx + (size_t)r * T;

  int c0 = 0, c1 = 0, c2 = 0;
  for (int k = 0; k < per; ++k) {
    int e = idxr[t0 + k];
    c0 += (e == 0); c1 += (e == 1); c2 += (e == 2);
  }
  int lane = tid & 63, wv = tid >> 6;
  int s0 = c0, s1 = c1, s2 = c2;  // wave inclusive scan
  for (int d = 1; d < 64; d <<= 1) {
    int u0 = __shfl_up(s0, d, 64);
    int u1 = __shfl_up(s1, d, 64);
    int u2 = __shfl_up(s2, d, 64);
    if (lane >= d) { s0 += u0; s1 += u1; s2 += u2; }
  }
  __shared__ int wsum[16][3];
  __shared__ int wbase[16][3];
  if (lane == 63) { wsum[wv][0] = s0; wsum[wv][1] = s1; wsum[wv][2] = s2; }
  __syncthreads();
  if (tid == 0) {
    int b0 = 0, b1 = 0, b2 = 0;
    int nw = blockDim.x >> 6;
    for (int i = 0; i < nw; ++i) {
      wbase[i][0] = b0; wbase[i][1] = b1; wbase[i][2] = b2;
      b0 += wsum[i][0]; b1 += wsum[i][1]; b2 += wsum[i][2];
    }
    counts[r * 3 + 0] = b0; counts[r * 3 + 1] = b1; counts[r * 3 + 2] = b2;
  }
  __syncthreads();
  int off[3];
  off[0] = wbase[wv][0] + s0 - c0;
  off[1] = wbase[wv][1] + s1 - c1;
  off[2] = wbase[wv][2] + s2 - c2;
  for (int k = 0; k < per; ++k) {
    int e = idxr[t0 + k];
    int p = off[e]++;
    perm[(size_t)(r * 3 + e) * T + p] = t0 + k;
    scale[(size_t)r * T + t0 + k] = (p < C) ? gv[(size_t)r * T + t0 + k] : 0.0f;
  }
}

// ---- kernel 3: grouped GEMM, BM=BN=256, BK=32, 8 waves, 4-deep LDS ring ----
// Diagnosis: at 128^2 tiles the 4608-block grid pushed ~23 TB/s of logical
// reads through L2 (vs ~34.5 TB/s ceiling) -> queuing-inflated load latency
// that depth-2 prefetch couldn't hide (MfmaUtil pinned ~21% across rounds
// 1-4 while conflicts/fetch fixes landed). 256^2 cuts logical L2 traffic
// 5.8x (396 blocks x 1 MB) and the 4-buffer ring gives stage distance 3
// tiles (~1200+ cy cover > L2 latency).
//
// Provable schedule, ONE counted vmcnt + ONE barrier per K-tile:
//   tile t: [s_waitcnt vmcnt(8); s_barrier]
//           ds_read 8 frags | STAGE A(t+3) | 16 MFMA (mt0-3)
//           ds_read 4 frags | STAGE B(t+3) | 16 MFMA (mt4-7)
// Proof: per wave per tile = 4 GLDS. At tile t's wait, allowed-outstanding 8
// = exactly tiles {t+1,t+2}; tile t's loads (staged at t-3) retired (in-order
// vmcnt), + barrier => all waves' tile-t loads landed before any tile-t
// ds_read. STAGE at t targets buf (t+3)%4, last read at tile t-1; every wave
// passed barrier(t) only after consuming its t-1 reads (compiler lgkm before
// MFMA) => no write-before-read race. Max skew = 1 tile region < ring slack.
__global__ __launch_bounds__(512, 2) void k_gemm(
    const unsigned short* __restrict__ xb,  // [3,T,H] bf16
    const unsigned short* __restrict__ wb,  // [3,3,H,H] bf16 (W[o][h])
    const float* __restrict__ be,           // [3,3,H] fp32
    const int* __restrict__ perm, const float* __restrict__ scale,
    const int* __restrict__ counts,
    float* __restrict__ out,                // [B,3,S,H] fp32
    int T) {
  // XCD chunking (bijective: 1152 = 8*144). Logical order (z, m, n-fastest):
  // the 4 n-siblings sharing one gathered A panel are consecutive -> same XCD.
  int p = blockIdx.x;                 // 0..1151
  int wg = (p & 7) * 144 + (p >> 3);
  int z = wg >> 7;                    // 0..8 (branch*3 + expert)
  int rem = wg & 127;
  int x = rem >> 2;                   // m-block 0..31
  int y = rem & 3;                    // n-block 0..3

  int r = z / 3;
  int count = counts[z];
  int m0 = x * 256;
  if (m0 >= count) return;
  int n0 = y * 256;

  __shared__ alignas(16) unsigned short As[4][256 * 32];  // 4 x 16KB ring
  __shared__ alignas(16) unsigned short Bs[4][256 * 32];  // 4 x 16KB ring
  __shared__ int toks[256];
  __shared__ float scl[256];
  __shared__ float bias_s[256];

  int tid = threadIdx.x;
  int lane = tid & 63;
  int w = tid >> 6;     // wave 0..7

  if (tid < 256) {
    int row = m0 + tid;
    int grow = row < count ? row : count - 1;  // clamp (valid addr, store-guarded)
    int tok = perm[(size_t)z * T + grow];
    toks[tid] = tok;
    scl[tid] = (row < count) ? scale[(size_t)r * T + tok] : 0.0f;
    bias_s[tid] = be[(size_t)z * HH + n0 + tid];
  }
  __syncthreads();  // toks ready; drains vmcnt -> pipeline counter starts at 0

  // staging: GLDS is linear (base + lane*16): lane l -> row base+(l>>2),
  // 16B slot l&3. Rotation swizzle (round-1-verified, 0 conflicts): LDS slot
  // j of a row holds global segment (j - ((row>>1)&3))&3, applied by
  // pre-rotating the per-lane GLOBAL source offset (rule 21).
  // 256-row tiles: 2 GLDS rounds per operand per wave (rows c*128 + w*16 ..).
  size_t aoff[2], boff[2];
  int sseg = ((lane & 3) - ((lane >> 3) & 3)) & 3;  // (l>>3)&3 == ((row&15)>>1)&3
#pragma unroll
  for (int c = 0; c < 2; ++c) {
    int rowl = c * 128 + w * 16 + (lane >> 2);
    int tok = toks[rowl];
    aoff[c] = (size_t)(r * T + tok) * HH + sseg * 8;
    boff[c] = ((size_t)z * HH + n0 + rowl) * HH + sseg * 8;  // W[n][h]
  }

  int wr = w >> 2;        // 0..1 -> m-offset wr*128 (wave owns 128 rows)
  int wc = w & 3;         // 0..3 -> n-offset wc*64
  int wm = wr * 128;
  int wn = wc * 64;
  floatx4 acc[8][4] = {};

  // read side: frag row = base16 + rl; slot = (q + ((rl>>1)&3))&3, q=lane>>4.
  // 64 lanes -> 8 (row-parity, slot) 16B-groups x 8 lanes = 2 lanes/bank: free.
  int rl = lane & 15;
  int rslot = (((lane >> 4) + ((rl >> 1) & 3)) & 3) * 8;  // elem offset in row

  auto STAGEA = [&](int tt) {
    int b_ = tt & 3;
    int kk_ = tt * 32;
    GLDS(xb + aoff[0] + kk_, &As[b_][(0 * 128 + w * 16) * 32]);
    GLDS(xb + aoff[1] + kk_, &As[b_][(1 * 128 + w * 16) * 32]);
  };
  auto STAGEB = [&](int tt) {
    int b_ = tt & 3;
    int kk_ = tt * 32;
    GLDS(wb + boff[0] + kk_, &Bs[b_][(0 * 128 + w * 16) * 32]);
    GLDS(wb + boff[1] + kk_, &Bs[b_][(1 * 128 + w * 16) * 32]);
  };
  // one K-tile body; stages tile t+3 when st=true
  auto TILE = [&](int t, bool st) {
    int b_ = t & 3;
    bf16x8 af[4], bq[4];
#pragma unroll
    for (int mt = 0; mt < 4; ++mt)
      af[mt] = *reinterpret_cast<const bf16x8*>(
          &As[b_][(wm + mt * 16 + rl) * 32 + rslot]);
#pragma unroll
    for (int nt = 0; nt < 4; ++nt)
      bq[nt] = *reinterpret_cast<const bf16x8*>(
          &Bs[b_][(wn + nt * 16 + rl) * 32 + rslot]);
    if (st) STAGEA(t + 3);
    __builtin_amdgcn_s_setprio(1);
#pragma unroll
    for (int mt = 0; mt < 4; ++mt)
#pragma unroll
      for (int nt = 0; nt < 4; ++nt)
        acc[mt][nt] = __builtin_amdgcn_mfma_f32_16x16x32_bf16(
            af[mt], bq[nt], acc[mt][nt], 0, 0, 0);
    __builtin_amdgcn_s_setprio(0);
#pragma unroll
    for (int mt = 0; mt < 4; ++mt)
      af[mt] = *reinterpret_cast<const bf16x8*>(
          &As[b_][(wm + 64 + mt * 16 + rl) * 32 + rslot]);
    if (st) STAGEB(t + 3);
    __builtin_amdgcn_s_setprio(1);
#pragma unroll
    for (int mt = 0; mt < 4; ++mt)
#pragma unroll
      for (int nt = 0; nt < 4; ++nt)
        acc[mt + 4][nt] = __builtin_amdgcn_mfma_f32_16x16x32_bf16(
            af[mt], bq[nt], acc[mt + 4][nt], 0, 0, 0);
    __builtin_amdgcn_s_setprio(0);
  };

  // prologue: stage tiles 0,1,2 (12 loads in flight)
  STAGEA(0); STAGEB(0);
  STAGEA(1); STAGEB(1);
  STAGEA(2); STAGEB(2);
  // main loop: K=1024 -> 32 tiles. Steady state: wait vmcnt(8) = tiles
  // {t+1,t+2} in flight; tail peeled with decreasing counts.
  for (int t = 0; t < 29; ++t) {
    asm volatile("s_waitcnt vmcnt(8)\n\ts_barrier" ::: "memory");
    TILE(t, true);
  }
  asm volatile("s_waitcnt vmcnt(8)\n\ts_barrier" ::: "memory");
  TILE(29, false);
  asm volatile("s_waitcnt vmcnt(4)\n\ts_barrier" ::: "memory");
  TILE(30, false);
  asm volatile("s_waitcnt vmcnt(0)\n\ts_barrier" ::: "memory");
  TILE(31, false);

  // epilogue: D row = (lane>>4)*4+reg, col = lane&15 (verified layout)
#pragma unroll
  for (int mt = 0; mt < 8; ++mt) {
#pragma unroll
    for (int rr = 0; rr < 4; ++rr) {
      int ml = wm + mt * 16 + (lane >> 4) * 4 + rr;
      if (m0 + ml < count) {
        float sc = scl[ml];
        int tok = toks[ml];
        size_t ob =
            (size_t)(((tok >> 10) * 3 + r) * SS + (tok & 1023)) * HH + n0;
#pragma unroll
        for (int nt = 0; nt < 4; ++nt) {
          int nl = wn + nt * 16 + rl;
          out[ob + nl] = sc * (acc[mt][nt][rr] + bias_s[nl]);
        }
      }
    }
  }
}

extern "C" void kernel_launch(void* const* d_in, const int* in_sizes, int n_in,
                              void* d_out, int out_size, void* d_ws,
                              size_t ws_size, hipStream_t stream) {
  const float* feat = (const float*)d_in[0];  // features fp32
  const float* gw   = (const float*)d_in[1];  // gate_w fp32
  const float* ew   = (const float*)d_in[2];  // expert_w fp32
  const float* eb   = (const float*)d_in[3];  // expert_b fp32
  float* out = (float*)d_out;

  int B = in_sizes[0] / (3 * SS * HH);
  int T = B * SS;                  // tokens per branch (8192)
  int C = (T + EE - 1) / EE;       // capacity = ceil(T/E) = 2731

  // workspace layout: xb bf16 [3,T,H] | wb bf16 [9,H,H] | ints/floats (~70 MB)
  unsigned short* xbuf = (unsigned short*)d_ws;           // 3*T*HH shorts
  unsigned short* wbuf = xbuf + (size_t)3 * T * HH;       // 9*HH*HH shorts
  int* perm   = (int*)(wbuf + (size_t)9 * HH * HH);       // 9*T
  int* counts = perm + (size_t)9 * T;                     // 16 (padded)
  int* idxb   = counts + 16;                              // 3*T
  float* gv   = (float*)(idxb + (size_t)3 * T);           // 3*T
  float* scl  = gv + (size_t)3 * T;                       // 3*T

  // route (1536 blocks) + weight conversion (1152 blocks) in one launch
  k_route<<<dim3(2688), dim3(256), 0, stream>>>(feat, gw, ew, xbuf, wbuf,
                                                idxb, gv, T);
  k_scan<<<dim3(3), dim3(1024), 0, stream>>>(idxb, gv, perm, scl, counts, T, C);
  k_gemm<<<dim3(1152), dim3(512), 0, stream>>>(
      xbuf, wbuf, eb, perm, scl, counts, out, T);
}